// Round 3
// baseline (374.186 us; speedup 1.0000x reference)
//
#include <hip/hip_runtime.h>
#include <hip/hip_bf16.h>

// SplitPool: x (B=8, L=65536, D=128) fp32; per-chunk mean over contiguous row
// runs; scatter to (B, 512, 128) with zero padding.
// R3 structure: scan+zero -> uniform 128-row tile sum w/ fp32 atomics -> combine.
// Rationale: fixed 64KB contiguous read per block (16 iters) amortizes per-block
// overhead 4x vs per-chunk splits and gives perfect load balance + linear
// blockIdx->address mapping.

#define SCAN_THREADS 256
#define TILE_ROWS 128  // rows per tile; 128 rows * 512B = 64KB per block

// Kernel 1: grid = SCAN_BLOCKS. Block 0 computes:
//  - chunk_start[c] = exclusive prefix sum of chunk_size (global flat row offset)
//  - pool_start[i]  = exclusive prefix sum of (n_peaks[i]+1)
// All blocks cooperatively zero sums[total_chunks*128].
#define SCAN_BLOCKS 64
__global__ __launch_bounds__(SCAN_THREADS) void scan_zero_kernel(
    const int* __restrict__ chunk_size, const int* __restrict__ n_peaks,
    int total_chunks, int batch,
    int* __restrict__ chunk_start, int* __restrict__ pool_start,
    float4* __restrict__ sums) {
  // zero the sums region (total_chunks*32 float4s) with all blocks
  const int nf4 = total_chunks * 32;
  for (int idx = blockIdx.x * SCAN_THREADS + threadIdx.x; idx < nf4;
       idx += SCAN_BLOCKS * SCAN_THREADS) {
    sums[idx] = make_float4(0.f, 0.f, 0.f, 0.f);
  }
  if (blockIdx.x != 0) return;

  __shared__ int partials[SCAN_THREADS];
  const int t = threadIdx.x;
  const int items = (total_chunks + SCAN_THREADS - 1) / SCAN_THREADS;
  const int begin = t * items;
  const int end = min(begin + items, total_chunks);

  int local = 0;
  for (int i = begin; i < end; ++i) local += chunk_size[i];
  partials[t] = local;
  __syncthreads();

  for (int off = 1; off < SCAN_THREADS; off <<= 1) {
    int v = (t >= off) ? partials[t - off] : 0;
    __syncthreads();
    partials[t] += v;
    __syncthreads();
  }

  int run = (t == 0) ? 0 : partials[t - 1];
  for (int i = begin; i < end; ++i) {
    chunk_start[i] = run;
    run += chunk_size[i];
  }

  if (t == 0) {
    int acc = 0;
    for (int i = 0; i < batch; ++i) {
      pool_start[i] = acc;
      acc += n_peaks[i] + 1;
    }
  }
}

// Kernel 2: one block per 128-row tile. 256 threads = 8 row-lanes x 32 dim4.
// Sums each chunk-segment overlapping the tile, atomicAdds into sums[c].
__global__ __launch_bounds__(256) void tile_sum_kernel(
    const float* __restrict__ x, const int* __restrict__ chunk_start,
    float* __restrict__ sums, int total_chunks, int total_rows) {
  const int t = threadIdx.x;
  const int dim4 = t & 31;
  const int r0 = t >> 5;
  const int tile_begin = blockIdx.x * TILE_ROWS;
  const int tile_end = min(tile_begin + TILE_ROWS, total_rows);

  // find c_lo: last chunk with chunk_start[c] <= tile_begin (redundant per thread)
  int lo = 0, hi = total_chunks - 1;
  while (lo < hi) {
    int mid = (lo + hi + 1) >> 1;
    if (chunk_start[mid] <= tile_begin) lo = mid; else hi = mid - 1;
  }
  int c = lo;

  const float4* __restrict__ xp = (const float4*)x;
  __shared__ float4 red[256];

  int seg_begin = tile_begin;
  while (seg_begin < tile_end) {
    const int chunk_end = (c + 1 < total_chunks) ? chunk_start[c + 1] : total_rows;
    const int seg_end = min(chunk_end, tile_end);

    float4 acc = make_float4(0.f, 0.f, 0.f, 0.f);
#pragma unroll 4
    for (int r = seg_begin + r0; r < seg_end; r += 8) {
      float4 v = xp[(size_t)r * 32 + dim4];
      acc.x += v.x; acc.y += v.y; acc.z += v.z; acc.w += v.w;
    }

    red[t] = acc;
    __syncthreads();
    if (t < 32) {
      float4 s = red[t];
#pragma unroll
      for (int k = 1; k < 8; ++k) {
        float4 v = red[t + 32 * k];
        s.x += v.x; s.y += v.y; s.z += v.z; s.w += v.w;
      }
      float* dst = sums + (size_t)c * 128 + t * 4;
      atomicAdd(dst + 0, s.x);
      atomicAdd(dst + 1, s.y);
      atomicAdd(dst + 2, s.z);
      atomicAdd(dst + 3, s.w);
    }
    __syncthreads();
    seg_begin = seg_end;
    ++c;
  }
}

// Kernel 3: combine + scale + scatter. 256 threads per block = 8 output slots.
__global__ __launch_bounds__(256) void combine_kernel(
    const float4* __restrict__ sums, const int* __restrict__ chunk_size,
    const int* __restrict__ n_peaks, const int* __restrict__ pool_start,
    float4* __restrict__ out, int max_n_peaks, int n_slots) {
  const int t = threadIdx.x;
  const int slot = blockIdx.x * 8 + (t >> 5);
  const int dim4 = t & 31;
  if (slot >= n_slots) return;
  const int i = slot / max_n_peaks;
  const int p = slot % max_n_peaks;

  float4 m = make_float4(0.f, 0.f, 0.f, 0.f);
  if (p < n_peaks[i]) {
    const int c = pool_start[i] + p;
    float4 s = sums[(size_t)c * 32 + dim4];
    const int sz = chunk_size[c];
    const float inv = 1.0f / (float)(sz > 0 ? sz : 1);
    m = make_float4(s.x * inv, s.y * inv, s.z * inv, s.w * inv);
  }
  out[(size_t)slot * 32 + dim4] = m;
}

extern "C" void kernel_launch(void* const* d_in, const int* in_sizes, int n_in,
                              void* d_out, int out_size, void* d_ws, size_t ws_size,
                              hipStream_t stream) {
  const float* x = (const float*)d_in[0];
  const int* chunk_size = (const int*)d_in[1];
  const int* n_peaks = (const int*)d_in[2];
  const int total_chunks = in_sizes[1];
  const int batch = in_sizes[2];
  const int dim = 128;                              // static per reference
  const int max_n_peaks = out_size / (batch * dim); // 512
  const int total_rows = in_sizes[0] / dim;         // B*L = 524288
  float* out = (float*)d_out;

  // ws layout: [chunk_start: total_chunks ints][pool_start: batch ints]
  // [pad 16B][sums: total_chunks*128 floats]
  int* chunk_start = (int*)d_ws;
  int* pool_start = chunk_start + total_chunks;
  size_t off = ((size_t)(total_chunks + batch) * sizeof(int) + 15) & ~(size_t)15;
  float* sums = (float*)((char*)d_ws + off);

  scan_zero_kernel<<<SCAN_BLOCKS, SCAN_THREADS, 0, stream>>>(
      chunk_size, n_peaks, total_chunks, batch, chunk_start, pool_start,
      (float4*)sums);

  const int n_tiles = (total_rows + TILE_ROWS - 1) / TILE_ROWS;  // 4096
  tile_sum_kernel<<<n_tiles, 256, 0, stream>>>(x, chunk_start, sums,
                                               total_chunks, total_rows);

  const int n_slots = batch * max_n_peaks;  // 4096
  combine_kernel<<<(n_slots + 7) / 8, 256, 0, stream>>>(
      (const float4*)sums, chunk_size, n_peaks, pool_start, (float4*)out,
      max_n_peaks, n_slots);
}

// Round 4
// 373.618 us; speedup vs baseline: 1.0015x; 1.0015x over previous
//
#include <hip/hip_runtime.h>
#include <hip/hip_bf16.h>

// SplitPool: x (B=8, L=65536, D=128) fp32; per-chunk mean over contiguous row
// runs; scatter to (B, 512, 128) zero-padded.
// R4 structure (2 launches):
//  1) scan_zero_out: block 0 scans chunk_size -> chunk_start (+sentinel) and
//     n_peaks -> pool_start (+sentinel); all 64 blocks zero d_out.
//  2) tile_sum_scatter: 2048 uniform 256-row tiles stream x; per chunk-segment
//     the partial is scaled by 1/chunk_size and atomicAdd'ed straight into out
//     (invalid trailing chunks skipped). No sums scratch, no combine launch.

#define SCAN_THREADS 256
#define SCAN_BLOCKS 64
#define TILE_ROWS 256  // 256 rows * 512B = 128KB per block; 2048 blocks = 1 pass

__global__ __launch_bounds__(SCAN_THREADS) void scan_zero_out_kernel(
    const int* __restrict__ chunk_size, const int* __restrict__ n_peaks,
    int total_chunks, int batch, int total_rows,
    int* __restrict__ chunk_start, int* __restrict__ pool_start,
    float4* __restrict__ out, int out_f4) {
  // zero d_out (poisoned 0xAA by harness) with all blocks
  for (int idx = blockIdx.x * SCAN_THREADS + threadIdx.x; idx < out_f4;
       idx += SCAN_BLOCKS * SCAN_THREADS) {
    out[idx] = make_float4(0.f, 0.f, 0.f, 0.f);
  }
  if (blockIdx.x != 0) return;

  __shared__ int partials[SCAN_THREADS];
  const int t = threadIdx.x;
  const int items = (total_chunks + SCAN_THREADS - 1) / SCAN_THREADS;
  const int begin = t * items;
  const int end = min(begin + items, total_chunks);

  int local = 0;
  for (int i = begin; i < end; ++i) local += chunk_size[i];
  partials[t] = local;
  __syncthreads();

  for (int off = 1; off < SCAN_THREADS; off <<= 1) {
    int v = (t >= off) ? partials[t - off] : 0;
    __syncthreads();
    partials[t] += v;
    __syncthreads();
  }

  int run = (t == 0) ? 0 : partials[t - 1];
  for (int i = begin; i < end; ++i) {
    chunk_start[i] = run;
    run += chunk_size[i];
  }

  if (t == 0) {
    chunk_start[total_chunks] = total_rows;  // sentinel
    int acc = 0;
    for (int i = 0; i < batch; ++i) {
      pool_start[i] = acc;
      acc += n_peaks[i] + 1;
    }
    pool_start[batch] = acc;  // sentinel
  }
}

// One block per 256-row tile. 256 threads = 8 row-lanes x 32 dim4.
// For each chunk-segment in the tile: accumulate, LDS-reduce, scale by
// 1/chunk_size, atomicAdd into out[sample, peak] (skip dropped trailing chunk).
__global__ __launch_bounds__(256, 8) void tile_sum_scatter_kernel(
    const float* __restrict__ x, const int* __restrict__ chunk_start,
    const int* __restrict__ pool_start, const int* __restrict__ n_peaks,
    float* __restrict__ out, int total_chunks, int total_rows, int batch,
    int max_n_peaks) {
  const int t = threadIdx.x;
  const int dim4 = t & 31;
  const int r0 = t >> 5;
  const int tile_begin = blockIdx.x * TILE_ROWS;
  const int tile_end = min(tile_begin + TILE_ROWS, total_rows);

  // last chunk with chunk_start[c] <= tile_begin (block-uniform)
  int lo = 0, hi = total_chunks - 1;
  while (lo < hi) {
    int mid = (lo + hi + 1) >> 1;
    if (chunk_start[mid] <= tile_begin) lo = mid; else hi = mid - 1;
  }
  int c = lo;
  // sample index of chunk c (block-uniform; batch=8 so linear scan is cheap)
  int samp = 0;
  while (pool_start[samp + 1] <= c) ++samp;

  const float4* __restrict__ xp = (const float4*)x;
  __shared__ float4 red[256];

  int seg_begin = tile_begin;
  int c_begin = chunk_start[c];
  while (seg_begin < tile_end) {
    const int c_end = chunk_start[c + 1];
    const int seg_end = min(c_end, tile_end);

    float4 acc = make_float4(0.f, 0.f, 0.f, 0.f);
#pragma unroll 4
    for (int r = seg_begin + r0; r < seg_end; r += 8) {
      float4 v = xp[(size_t)r * 32 + dim4];
      acc.x += v.x; acc.y += v.y; acc.z += v.z; acc.w += v.w;
    }

    red[t] = acc;
    __syncthreads();

    // dropped trailing chunk of sample `samp` is c == pool_start[samp+1]-1
    const int peak = c - pool_start[samp];
    const bool valid = peak < n_peaks[samp];
    if (valid && t < 32) {
      float4 s = red[t];
#pragma unroll
      for (int k = 1; k < 8; ++k) {
        float4 v = red[t + 32 * k];
        s.x += v.x; s.y += v.y; s.z += v.z; s.w += v.w;
      }
      const int sz = c_end - c_begin;
      const float inv = 1.0f / (float)(sz > 0 ? sz : 1);
      float* dst = out + ((size_t)samp * max_n_peaks + peak) * 128 + t * 4;
      atomicAdd(dst + 0, s.x * inv);
      atomicAdd(dst + 1, s.y * inv);
      atomicAdd(dst + 2, s.z * inv);
      atomicAdd(dst + 3, s.w * inv);
    }
    __syncthreads();

    seg_begin = seg_end;
    ++c;
    c_begin = c_end;
    if (pool_start[samp + 1] <= c) ++samp;
  }
}

extern "C" void kernel_launch(void* const* d_in, const int* in_sizes, int n_in,
                              void* d_out, int out_size, void* d_ws, size_t ws_size,
                              hipStream_t stream) {
  const float* x = (const float*)d_in[0];
  const int* chunk_size = (const int*)d_in[1];
  const int* n_peaks = (const int*)d_in[2];
  const int total_chunks = in_sizes[1];
  const int batch = in_sizes[2];
  const int dim = 128;                              // static per reference
  const int max_n_peaks = out_size / (batch * dim); // 512
  const int total_rows = in_sizes[0] / dim;         // B*L = 524288
  float* out = (float*)d_out;

  // ws layout: [chunk_start: total_chunks+1][pool_start: batch+1]
  int* chunk_start = (int*)d_ws;
  int* pool_start = chunk_start + (total_chunks + 1);

  scan_zero_out_kernel<<<SCAN_BLOCKS, SCAN_THREADS, 0, stream>>>(
      chunk_size, n_peaks, total_chunks, batch, total_rows, chunk_start,
      pool_start, (float4*)out, out_size / 4);

  const int n_tiles = (total_rows + TILE_ROWS - 1) / TILE_ROWS;  // 2048
  tile_sum_scatter_kernel<<<n_tiles, 256, 0, stream>>>(
      x, chunk_start, pool_start, n_peaks, out, total_chunks, total_rows,
      batch, max_n_peaks);
}